// Round 4
// baseline (345.982 us; speedup 1.0000x reference)
//
#include <hip/hip_runtime.h>

#define NE 32
#define NT 2048
#define NH 1024
#define NI 512
#define NK 4
#define CAP 512

typedef __attribute__((ext_vector_type(8))) short short8;
typedef __attribute__((ext_vector_type(4))) float floatx4;

// ---- fp32 -> bf16 (RNE) pair pack -> one dword ----
static __device__ __forceinline__ unsigned pk_bf16(float x, float y) {
#if __has_builtin(__builtin_amdgcn_cvt_pk_bf16_f32)
    typedef __attribute__((ext_vector_type(2))) __bf16 bf16x2;
    union { bf16x2 v; unsigned u; } c;
    c.v = __builtin_amdgcn_cvt_pk_bf16_f32(x, y);
    return c.u;
#else
    union { float f; unsigned u; } a, b;
    a.f = x; b.f = y;
    unsigned ua = (a.u + 0x7fffu + ((a.u >> 16) & 1u)) >> 16;
    unsigned ub = (b.u + 0x7fffu + ((b.u >> 16) & 1u)) >> 16;
    return (ua & 0xffffu) | (ub << 16);
#endif
}

static __device__ __forceinline__ short8 pack8(const float* p) {
    union { unsigned u[4]; short8 s; } c;
    c.u[0] = pk_bf16(p[0], p[1]);
    c.u[1] = pk_bf16(p[2], p[3]);
    c.u[2] = pk_bf16(p[4], p[5]);
    c.u[3] = pk_bf16(p[6], p[7]);
    return c.s;
}

static __device__ __forceinline__ unsigned short bf16_1(float x) {
    return (unsigned short)(pk_bf16(x, 0.f) & 0xffffu);
}

// ---------------- routing ----------------
__global__ void route_kernel(const int* __restrict__ idx,
                             const float* __restrict__ w,
                             int* __restrict__ counts,
                             int* __restrict__ tok,
                             float* __restrict__ wgt) {
    int tid = blockIdx.x * blockDim.x + threadIdx.x;
    if (tid >= NT * NK) return;
    int e = idx[tid];
    int pos = atomicAdd(&counts[e], 1);
    if (pos < CAP) {
        tok[e * CAP + pos] = tid;          // tid = t*NK + k
        wgt[e * CAP + pos] = w[tid];
    }
}

// ---------------- hidden fp32 -> bf16 ----------------
__global__ void cvt_hidden(const float* __restrict__ hidden,
                           unsigned short* __restrict__ hb16) {
    size_t i = (size_t)(blockIdx.x * 256 + threadIdx.x) * 8;
    float tmp[8];
    *(floatx4*)tmp       = *(const floatx4*)(hidden + i);
    *(floatx4*)(tmp + 4) = *(const floatx4*)(hidden + i + 4);
    *(short8*)(hb16 + i) = pack8(tmp);
}

// LDS tiles: [2 bufs][128 rows][8 granules of 8 bf16], rows = 128B (no pad),
// granule XOR-swizzled: logical granule g of row r lives at slot g^(r&7).
// Frag reads (fixed g, rows lcol 0..15) hit 8 distinct slots x2 => 2-way, free.

// ---------------- gate/up MFMA GEMM + SiLU ----------------
// tile: 128 entries x 64 j; B-rows: 64 gate + 64 up. waves: wm x wj (2x2).
// Each wave holds gate (nt0,1) AND up (nt2,3) for the same (m,j) => in-reg SiLU.
__global__ __launch_bounds__(256, 2) void gateup_mfma(
    const unsigned short* __restrict__ hb16,   // [NT][NH] bf16
    const float* __restrict__ gup,             // [NE][2*NI][NH] fp32
    const int* __restrict__ counts,
    const int* __restrict__ tok,
    unsigned short* __restrict__ hbuf)         // [NT*NK][NI] bf16
{
    int e = blockIdx.z;
    int cnt = counts[e]; if (cnt > CAP) cnt = CAP;
    int m0 = blockIdx.y * 128;
    if (m0 >= cnt) return;
    int j0 = blockIdx.x * 64;

    __shared__ __align__(16) short As[2][128][64];   // 32 KB
    __shared__ __align__(16) short Bs[2][128][64];   // 32 KB

    int tid = threadIdx.x;
    int sr = tid >> 3;          // 0..31 (row within pass)
    int sg = tid & 7;           // granule 0..7

    const unsigned short* aptr[4];
    short* awr[4];
    const float* bptr[4];
    short* bwr[4];
    const float* gup_e = gup + (size_t)e * (2 * NI) * NH;
#pragma unroll
    for (int p = 0; p < 4; p++) {
        int r = p * 32 + sr;
        int mi = m0 + r;
        int tk = tok[e * CAP + (mi < cnt ? mi : m0)];
        aptr[p] = hb16 + (size_t)(tk >> 2) * NH + sg * 8;
        awr[p]  = &As[0][r][(sg ^ (r & 7)) * 8];
        int gj = (r < 64) ? (j0 + r) : (NI + j0 + (r - 64));
        bptr[p] = gup_e + (size_t)gj * NH + sg * 8;
        bwr[p]  = &Bs[0][r][(sg ^ (r & 7)) * 8];
    }

    int wave = tid >> 6, lane = tid & 63;
    int wm = wave >> 1;          // m half
    int wj = wave & 1;           // j half (32 cols)
    int lcol = lane & 15;
    int quad = lane >> 4;

    floatx4 acc[4][4];
#pragma unroll
    for (int a = 0; a < 4; a++)
#pragma unroll
        for (int b = 0; b < 4; b++) acc[a][b] = (floatx4){0.f, 0.f, 0.f, 0.f};

    short8 ra[4];
    float4 rb[8];
    // ---- prologue: tile 0 ----
#pragma unroll
    for (int p = 0; p < 4; p++) {
        ra[p] = *(const short8*)(aptr[p]);
        rb[2 * p]     = *(const float4*)(bptr[p]);
        rb[2 * p + 1] = *(const float4*)(bptr[p] + 4);
    }
#pragma unroll
    for (int p = 0; p < 4; p++) {
        *(short8*)(awr[p]) = ra[p];
        union { unsigned u[4]; short8 s; } c;
        c.u[0] = pk_bf16(rb[2 * p].x, rb[2 * p].y);
        c.u[1] = pk_bf16(rb[2 * p].z, rb[2 * p].w);
        c.u[2] = pk_bf16(rb[2 * p + 1].x, rb[2 * p + 1].y);
        c.u[3] = pk_bf16(rb[2 * p + 1].z, rb[2 * p + 1].w);
        *(short8*)(bwr[p]) = c.s;
    }
    // prefetch tile 1
#pragma unroll
    for (int p = 0; p < 4; p++) {
        ra[p] = *(const short8*)(aptr[p] + 64);
        rb[2 * p]     = *(const float4*)(bptr[p] + 64);
        rb[2 * p + 1] = *(const float4*)(bptr[p] + 68);
    }
    __syncthreads();

    const int NIT = NH / 64;   // 16
    for (int it = 0; it < NIT; ++it) {
        int cur = it & 1;
        int co = cur * 8192;         // short offset between buffers
#pragma unroll
        for (int ks = 0; ks < 2; ks++) {
            short8 af[4], bfr[4];
            int q = ks * 4 + quad;
#pragma unroll
            for (int mt = 0; mt < 4; mt++) {
                int R = wm * 64 + mt * 16 + lcol;
                af[mt] = *(const short8*)&As[cur][R][(q ^ (R & 7)) * 8];
            }
#pragma unroll
            for (int nt = 0; nt < 4; nt++) {
                int R = (nt < 2) ? (wj * 32 + nt * 16 + lcol)
                                 : (64 + wj * 32 + (nt - 2) * 16 + lcol);
                bfr[nt] = *(const short8*)&Bs[cur][R][(q ^ (R & 7)) * 8];
            }
#pragma unroll
            for (int mt = 0; mt < 4; mt++)
#pragma unroll
                for (int nt = 0; nt < 4; nt++)
                    acc[mt][nt] = __builtin_amdgcn_mfma_f32_16x16x32_bf16(
                        af[mt], bfr[nt], acc[mt][nt], 0, 0, 0);
        }
        if (it + 1 < NIT) {
            int no = (co ^ 8192);
#pragma unroll
            for (int p = 0; p < 4; p++) {
                *(short8*)(awr[p] + no) = ra[p];
                union { unsigned u[4]; short8 s; } c;
                c.u[0] = pk_bf16(rb[2 * p].x, rb[2 * p].y);
                c.u[1] = pk_bf16(rb[2 * p].z, rb[2 * p].w);
                c.u[2] = pk_bf16(rb[2 * p + 1].x, rb[2 * p + 1].y);
                c.u[3] = pk_bf16(rb[2 * p + 1].z, rb[2 * p + 1].w);
                *(short8*)(bwr[p] + no) = c.s;
            }
            if (it + 2 < NIT) {
                int h2 = (it + 2) * 64;
#pragma unroll
                for (int p = 0; p < 4; p++) {
                    ra[p] = *(const short8*)(aptr[p] + h2);
                    rb[2 * p]     = *(const float4*)(bptr[p] + h2);
                    rb[2 * p + 1] = *(const float4*)(bptr[p] + h2 + 4);
                }
            }
            __syncthreads();
        }
    }

    // ---- epilogue: in-register SiLU fuse, scalar bf16 stores ----
#pragma unroll
    for (int mt = 0; mt < 4; mt++) {
#pragma unroll
        for (int i = 0; i < 4; i++) {
            int m = wm * 64 + mt * 16 + quad * 4 + i;
            if (m0 + m < cnt) {
                int tk = tok[e * CAP + m0 + m];
                unsigned short* hp = hbuf + (size_t)tk * NI + j0 + wj * 32 + lcol;
#pragma unroll
                for (int nt = 0; nt < 2; nt++) {
                    float g = acc[mt][nt][i];
                    float u = acc[mt][nt + 2][i];
                    float h = g / (1.f + __expf(-g)) * u;
                    hp[nt * 16] = bf16_1(h);
                }
            }
        }
    }
}

// ---------------- down MFMA GEMM + weight-scale + atomic accumulate ----------------
// tile: 128 entries x 128 H-cols, BK=64 over NI (8 iters), waves 2x2
__global__ __launch_bounds__(256, 2) void down_mfma(
    const unsigned short* __restrict__ hbuf,   // [NT*NK][NI] bf16
    const float* __restrict__ down,            // [NE][NH][NI] fp32
    const int* __restrict__ counts,
    const int* __restrict__ tok,
    const float* __restrict__ wgt,
    float* __restrict__ out)                   // [NT][NH] fp32
{
    int e = blockIdx.z;
    int cnt = counts[e]; if (cnt > CAP) cnt = CAP;
    int m0 = blockIdx.y * 128;
    if (m0 >= cnt) return;
    int n0 = blockIdx.x * 128;

    __shared__ __align__(16) short As[2][128][64];
    __shared__ __align__(16) short Bs[2][128][64];

    int tid = threadIdx.x;
    int sr = tid >> 3;
    int sg = tid & 7;

    const unsigned short* aptr[4];
    short* awr[4];
    const float* bptr[4];
    short* bwr[4];
    const float* down_e = down + (size_t)e * NH * NI;
#pragma unroll
    for (int p = 0; p < 4; p++) {
        int r = p * 32 + sr;
        int mi = m0 + r;
        int tk = tok[e * CAP + (mi < cnt ? mi : m0)];
        aptr[p] = hbuf + (size_t)tk * NI + sg * 8;
        awr[p]  = &As[0][r][(sg ^ (r & 7)) * 8];
        bptr[p] = down_e + (size_t)(n0 + r) * NI + sg * 8;
        bwr[p]  = &Bs[0][r][(sg ^ (r & 7)) * 8];
    }

    int wave = tid >> 6, lane = tid & 63;
    int wm = wave >> 1, wn = wave & 1;
    int lcol = lane & 15;
    int quad = lane >> 4;

    floatx4 acc[4][4];
#pragma unroll
    for (int a = 0; a < 4; a++)
#pragma unroll
        for (int b = 0; b < 4; b++) acc[a][b] = (floatx4){0.f, 0.f, 0.f, 0.f};

    short8 ra[4];
    float4 rb[8];
#pragma unroll
    for (int p = 0; p < 4; p++) {
        ra[p] = *(const short8*)(aptr[p]);
        rb[2 * p]     = *(const float4*)(bptr[p]);
        rb[2 * p + 1] = *(const float4*)(bptr[p] + 4);
    }
#pragma unroll
    for (int p = 0; p < 4; p++) {
        *(short8*)(awr[p]) = ra[p];
        union { unsigned u[4]; short8 s; } c;
        c.u[0] = pk_bf16(rb[2 * p].x, rb[2 * p].y);
        c.u[1] = pk_bf16(rb[2 * p].z, rb[2 * p].w);
        c.u[2] = pk_bf16(rb[2 * p + 1].x, rb[2 * p + 1].y);
        c.u[3] = pk_bf16(rb[2 * p + 1].z, rb[2 * p + 1].w);
        *(short8*)(bwr[p]) = c.s;
    }
#pragma unroll
    for (int p = 0; p < 4; p++) {
        ra[p] = *(const short8*)(aptr[p] + 64);
        rb[2 * p]     = *(const float4*)(bptr[p] + 64);
        rb[2 * p + 1] = *(const float4*)(bptr[p] + 68);
    }
    __syncthreads();

    const int NIT = NI / 64;   // 8
    for (int it = 0; it < NIT; ++it) {
        int cur = it & 1;
#pragma unroll
        for (int ks = 0; ks < 2; ks++) {
            short8 af[4], bfr[4];
            int q = ks * 4 + quad;
#pragma unroll
            for (int mt = 0; mt < 4; mt++) {
                int R = wm * 64 + mt * 16 + lcol;
                af[mt] = *(const short8*)&As[cur][R][(q ^ (R & 7)) * 8];
            }
#pragma unroll
            for (int nt = 0; nt < 4; nt++) {
                int R = wn * 64 + nt * 16 + lcol;
                bfr[nt] = *(const short8*)&Bs[cur][R][(q ^ (R & 7)) * 8];
            }
#pragma unroll
            for (int mt = 0; mt < 4; mt++)
#pragma unroll
                for (int nt = 0; nt < 4; nt++)
                    acc[mt][nt] = __builtin_amdgcn_mfma_f32_16x16x32_bf16(
                        af[mt], bfr[nt], acc[mt][nt], 0, 0, 0);
        }
        if (it + 1 < NIT) {
            int no = ((cur ^ 1)) * 8192;
#pragma unroll
            for (int p = 0; p < 4; p++) {
                *(short8*)(awr[p] + no) = ra[p];
                union { unsigned u[4]; short8 s; } c;
                c.u[0] = pk_bf16(rb[2 * p].x, rb[2 * p].y);
                c.u[1] = pk_bf16(rb[2 * p].z, rb[2 * p].w);
                c.u[2] = pk_bf16(rb[2 * p + 1].x, rb[2 * p + 1].y);
                c.u[3] = pk_bf16(rb[2 * p + 1].z, rb[2 * p + 1].w);
                *(short8*)(bwr[p] + no) = c.s;
            }
            if (it + 2 < NIT) {
                int i2 = (it + 2) * 64;
#pragma unroll
                for (int p = 0; p < 4; p++) {
                    ra[p] = *(const short8*)(aptr[p] + i2);
                    rb[2 * p]     = *(const float4*)(bptr[p] + i2);
                    rb[2 * p + 1] = *(const float4*)(bptr[p] + i2 + 4);
                }
            }
            __syncthreads();
        }
    }

#pragma unroll
    for (int mt = 0; mt < 4; mt++)
#pragma unroll
        for (int i = 0; i < 4; i++) {
            int m = wm * 64 + mt * 16 + quad * 4 + i;
            if (m0 + m < cnt) {
                int tk = tok[e * CAP + m0 + m];
                float wl = wgt[e * CAP + m0 + m];
                float* op = out + (size_t)(tk >> 2) * NH + n0 + wn * 64 + lcol;
#pragma unroll
                for (int nt = 0; nt < 4; nt++)
                    atomicAdd(op + nt * 16, acc[mt][nt][i] * wl);
            }
        }
}

extern "C" void kernel_launch(void* const* d_in, const int* in_sizes, int n_in,
                              void* d_out, int out_size, void* d_ws, size_t ws_size,
                              hipStream_t stream) {
    const float* hidden = (const float*)d_in[0];
    const int*   tk_idx = (const int*)d_in[1];
    const float* tk_w   = (const float*)d_in[2];
    const float* gup    = (const float*)d_in[3];
    const float* down   = (const float*)d_in[4];
    float* out = (float*)d_out;

    char* ws = (char*)d_ws;
    int*            counts = (int*)ws;                              // 256 B
    int*            tok    = (int*)(ws + 256);                      // 64 KB
    float*          wgt    = (float*)(ws + 256 + NE * CAP * 4);     // 64 KB
    unsigned short* hb16   = (unsigned short*)(ws + 256 + 2 * NE * CAP * 4);          // 4 MB
    unsigned short* hbuf   = (unsigned short*)(ws + 256 + 2 * NE * CAP * 4
                                               + (size_t)NT * NH * 2);                // 8.4 MB

    hipMemsetAsync(counts, 0, 256, stream);
    hipMemsetAsync(out, 0, (size_t)NT * NH * sizeof(float), stream);

    route_kernel<<<(NT * NK + 255) / 256, 256, 0, stream>>>(tk_idx, tk_w, counts, tok, wgt);
    cvt_hidden<<<(NT * NH / 8) / 256, 256, 0, stream>>>(hidden, hb16);

    dim3 gridG(NI / 64, CAP / 128, NE);    // (8, 4, 32)
    gateup_mfma<<<gridG, 256, 0, stream>>>(hb16, gup, counts, tok, hbuf);

    dim3 gridD(NH / 128, CAP / 128, NE);   // (8, 4, 32)
    down_mfma<<<gridD, 256, 0, stream>>>(hbuf, down, counts, tok, wgt, out);
}